// Round 1
// baseline (539.149 us; speedup 1.0000x reference)
//
#include <hip/hip_runtime.h>
#include <hip/hip_bf16.h>
#include <math.h>

// Problem dims
#define B_   4
#define S_   2048
#define D_   1024
#define H_   16
#define DH_  64
#define M_   (B_ * S_)      // 8192
#define N_   (H_ * DH_)     // 1024

typedef _Float16 f16;
typedef __attribute__((ext_vector_type(4))) _Float16 f16x4;
typedef __attribute__((ext_vector_type(8))) _Float16 f16x8;
typedef __attribute__((ext_vector_type(4))) float    f32x4;

// ---------------------------------------------------------------------------
// async global -> LDS, 16B per lane. LDS dest must be wave-uniform base;
// HW writes base + lane*16.
__device__ __forceinline__ void async_cp16(const void* g, void* l) {
  __builtin_amdgcn_global_load_lds(
      (const __attribute__((address_space(1))) unsigned int*)g,
      (__attribute__((address_space(3))) unsigned int*)l, 16, 0, 0);
}

// ---------------------------------------------------------------------------
// f32 -> f16 elementwise (vectorized 4-wide)
__global__ __launch_bounds__(256) void cvt_f32_f16(const float* __restrict__ in,
                                                   f16* __restrict__ out, int n4) {
  int i = blockIdx.x * 256 + threadIdx.x;
  if (i < n4) {
    f32x4 v = ((const f32x4*)in)[i];
    ((f16x4*)out)[i] = __builtin_convertvector(v, f16x4);
  }
}

// ---------------------------------------------------------------------------
// Weight transpose+cast: W [1024 x 1024] f32 row-major -> Wt [1024 x 1024] f16
// (Wt[n][k] = W[k][n]).  blockIdx.z selects which of the 4 weights.
__global__ __launch_bounds__(256) void transpose_w(
    const float* __restrict__ W0, const float* __restrict__ W1,
    const float* __restrict__ W2, const float* __restrict__ W3,
    f16* __restrict__ T0, f16* __restrict__ T1,
    f16* __restrict__ T2, f16* __restrict__ T3) {
  const float* W = (blockIdx.z == 0) ? W0 : (blockIdx.z == 1) ? W1
                 : (blockIdx.z == 2) ? W2 : W3;
  f16* T = (blockIdx.z == 0) ? T0 : (blockIdx.z == 1) ? T1
         : (blockIdx.z == 2) ? T2 : T3;
  __shared__ float tile[32][33];
  int x  = blockIdx.x * 32 + threadIdx.x;   // col in W
  int y0 = blockIdx.y * 32 + threadIdx.y;   // row in W
#pragma unroll
  for (int i = 0; i < 32; i += 8)
    tile[threadIdx.y + i][threadIdx.x] = W[(size_t)(y0 + i) * 1024 + x];
  __syncthreads();
  int tx  = blockIdx.y * 32 + threadIdx.x;  // col in T (= row in W)
  int ty0 = blockIdx.x * 32 + threadIdx.y;  // row in T (= col in W)
#pragma unroll
  for (int i = 0; i < 32; i += 8)
    T[(size_t)(ty0 + i) * 1024 + tx] = (f16)tile[threadIdx.x][threadIdx.y + i];
}

// ---------------------------------------------------------------------------
// v [B,S,H,DH] f16  ->  vt [B,H,DH,S] f16   (64x64 tiles per (b,h))
__global__ __launch_bounds__(256) void transpose_v(const f16* __restrict__ v,
                                                   f16* __restrict__ vt) {
  int bh = blockIdx.y;              // b*16 + h
  int b  = bh >> 4, h = bh & 15;
  int s0 = blockIdx.x * 64;
  __shared__ f16 tile[64][72];      // +8 pad breaks bank conflicts
  int tid = threadIdx.x;
#pragma unroll
  for (int it = 0; it < 16; ++it) {
    int idx = it * 256 + tid;
    int r = idx >> 6, c = idx & 63;           // r: s-offset, c: f
    tile[r][c] = v[((size_t)(b * S_ + s0 + r)) * N_ + h * DH_ + c];
  }
  __syncthreads();
#pragma unroll
  for (int it = 0; it < 16; ++it) {
    int idx = it * 256 + tid;
    int fr = idx >> 6, sc = idx & 63;         // fr: f, sc: s-offset
    vt[((size_t)bh * DH_ + fr) * S_ + s0 + sc] = tile[sc][fr];
  }
}

// ---------------------------------------------------------------------------
// GEMM: C[M,N] = A[M,K] * Bt[N,K]^T, f16 in, f32 accum.
// epilogue: (acc + bias[col]) * scale -> f16 (OUT_F32=false) or f32.
// 128x128 tile, BK=64, 256 threads (2x2 waves, 64x64 per wave).
template <bool OUT_F32>
__global__ __launch_bounds__(256) void gemm_bt(
    const f16* __restrict__ A, const f16* __restrict__ Bt,
    const float* __restrict__ bias, float scale,
    void* __restrict__ outp, int M, int N, int K) {
  __shared__ f16 lA[128 * 64];
  __shared__ f16 lB[128 * 64];
  const int tid  = threadIdx.x;
  const int lane = tid & 63, wid = tid >> 6;
  const int wr = wid >> 1, wc = wid & 1;
  const int tile_m = blockIdx.y * 128, tile_n = blockIdx.x * 128;
  const int l8 = lane >> 3, c8 = (lane & 7) * 8;
  const int r15 = lane & 15, hi = lane >> 4;

  f32x4 acc[4][4];
#pragma unroll
  for (int m = 0; m < 4; ++m)
#pragma unroll
    for (int n = 0; n < 4; ++n) acc[m][n] = (f32x4)(0.f);

  for (int kt = 0; kt < K; kt += 64) {
#pragma unroll
    for (int i = 0; i < 4; ++i) {
      int rb = wid * 32 + i * 8;  // wave-uniform row block (8 rows = 1KB)
      async_cp16(A  + (size_t)(tile_m + rb + l8) * K + kt + c8, &lA[rb * 64]);
      async_cp16(Bt + (size_t)(tile_n + rb + l8) * K + kt + c8, &lB[rb * 64]);
    }
    __syncthreads();
#pragma unroll
    for (int kk = 0; kk < 2; ++kk) {
      f16x8 af[4], bf[4];
#pragma unroll
      for (int m = 0; m < 4; ++m)
        af[m] = *(const f16x8*)&lA[(wr * 64 + m * 16 + r15) * 64 + kk * 32 + hi * 8];
#pragma unroll
      for (int n = 0; n < 4; ++n)
        bf[n] = *(const f16x8*)&lB[(wc * 64 + n * 16 + r15) * 64 + kk * 32 + hi * 8];
#pragma unroll
      for (int m = 0; m < 4; ++m)
#pragma unroll
        for (int n = 0; n < 4; ++n)
          acc[m][n] = __builtin_amdgcn_mfma_f32_16x16x32_f16(af[m], bf[n], acc[m][n], 0, 0, 0);
    }
    __syncthreads();
  }

#pragma unroll
  for (int m = 0; m < 4; ++m) {
    int row0 = tile_m + wr * 64 + m * 16 + hi * 4;
#pragma unroll
    for (int n = 0; n < 4; ++n) {
      int col = tile_n + wc * 64 + n * 16 + r15;
      float bv = bias[col];
#pragma unroll
      for (int r = 0; r < 4; ++r) {
        float v = (acc[m][n][r] + bv) * scale;
        if (OUT_F32)
          ((float*)outp)[(size_t)(row0 + r) * N + col] = v;
        else
          ((f16*)outp)[(size_t)(row0 + r) * N + col] = (f16)v;
      }
    }
  }
}

// ---------------------------------------------------------------------------
// Flash attention. Grid: (S/256, B*H). 256 threads = 4 waves; each wave owns
// 64 q-rows. KV tiles of 64 staged in LDS (shared by the 4 waves).
// q, k: [B,S,H,DH] f16 (q pre-scaled by 1/8, biases folded).
// vt:   [B,H,DH,S] f16.   x out: [B,S,H,DH] f16.
__global__ __launch_bounds__(256) void attn(
    const f16* __restrict__ q, const f16* __restrict__ k,
    const f16* __restrict__ vt, f16* __restrict__ x) {
  __shared__ f16 lK[64 * 64];
  __shared__ f16 lV[64 * 64];
  __shared__ f16 lP[4][64 * 64];
  const int tid = threadIdx.x, lane = tid & 63, wid = tid >> 6;
  const int bh = blockIdx.y, b = bh >> 4, h = bh & 15;
  const int q0 = blockIdx.x * 256 + wid * 64;
  const int r15 = lane & 15, hi = lane >> 4;
  const int l8 = lane >> 3, c8 = (lane & 7) * 8;

  const f16* qb = q + (size_t)b * S_ * N_ + h * DH_;
  const f16* kb = k + (size_t)b * S_ * N_ + h * DH_;
  const f16* vb = vt + (size_t)bh * DH_ * S_;

  // Q fragments in registers: 4 m-frags x 2 k-halves
  f16x8 qf[4][2];
#pragma unroll
  for (int m = 0; m < 4; ++m)
#pragma unroll
    for (int kk = 0; kk < 2; ++kk)
      qf[m][kk] = *(const f16x8*)(qb + (size_t)(q0 + m * 16 + r15) * N_ + kk * 32 + hi * 8);

  f32x4 xa[4][4];
#pragma unroll
  for (int m = 0; m < 4; ++m)
#pragma unroll
    for (int n = 0; n < 4; ++n) xa[m][n] = (f32x4)(0.f);
  float rm[4][4], rl[4][4];
#pragma unroll
  for (int m = 0; m < 4; ++m)
#pragma unroll
    for (int r = 0; r < 4; ++r) { rm[m][r] = -INFINITY; rl[m][r] = 0.f; }

  for (int j0 = 0; j0 < S_; j0 += 64) {
    // stage K tile [64 j][64 f] and Vt tile [64 f][64 j]
#pragma unroll
    for (int i = 0; i < 2; ++i) {
      int rb = wid * 16 + i * 8;
      async_cp16(kb + (size_t)(j0 + rb + l8) * N_ + c8, &lK[rb * 64]);
      async_cp16(vb + (size_t)(rb + l8) * S_ + j0 + c8, &lV[rb * 64]);
    }
    __syncthreads();

    // ---- QK^T ----
    f32x4 sa[4][4];
#pragma unroll
    for (int m = 0; m < 4; ++m)
#pragma unroll
      for (int n = 0; n < 4; ++n) sa[m][n] = (f32x4)(0.f);
#pragma unroll
    for (int kk = 0; kk < 2; ++kk) {
      f16x8 kf[4];
#pragma unroll
      for (int n = 0; n < 4; ++n)
        kf[n] = *(const f16x8*)&lK[(n * 16 + r15) * 64 + kk * 32 + hi * 8];
#pragma unroll
      for (int m = 0; m < 4; ++m)
#pragma unroll
        for (int n = 0; n < 4; ++n)
          sa[m][n] = __builtin_amdgcn_mfma_f32_16x16x32_f16(qf[m][kk], kf[n], sa[m][n], 0, 0, 0);
    }

    // ---- online softmax ----
    float tmax[4][4];
#pragma unroll
    for (int m = 0; m < 4; ++m)
#pragma unroll
      for (int r = 0; r < 4; ++r)
        tmax[m][r] = fmaxf(fmaxf(sa[m][0][r], sa[m][1][r]), fmaxf(sa[m][2][r], sa[m][3][r]));
#pragma unroll
    for (int mask = 1; mask < 16; mask <<= 1)
#pragma unroll
      for (int m = 0; m < 4; ++m)
#pragma unroll
        for (int r = 0; r < 4; ++r)
          tmax[m][r] = fmaxf(tmax[m][r], __shfl_xor(tmax[m][r], mask, 64));

    float fac[4][4];
#pragma unroll
    for (int m = 0; m < 4; ++m)
#pragma unroll
      for (int r = 0; r < 4; ++r) {
        float nm = fmaxf(rm[m][r], tmax[m][r]);
        fac[m][r] = __expf(rm[m][r] - nm);   // 0 on first tile (rm=-inf)
        rm[m][r] = nm;
      }

    float tsum[4][4];
#pragma unroll
    for (int m = 0; m < 4; ++m)
#pragma unroll
      for (int r = 0; r < 4; ++r) tsum[m][r] = 0.f;
#pragma unroll
    for (int m = 0; m < 4; ++m)
#pragma unroll
      for (int n = 0; n < 4; ++n)
#pragma unroll
        for (int r = 0; r < 4; ++r) {
          float p = __expf(sa[m][n][r] - rm[m][r]);
          tsum[m][r] += p;
          lP[wid][(m * 16 + hi * 4 + r) * 64 + n * 16 + r15] = (f16)p;
        }
#pragma unroll
    for (int mask = 1; mask < 16; mask <<= 1)
#pragma unroll
      for (int m = 0; m < 4; ++m)
#pragma unroll
        for (int r = 0; r < 4; ++r)
          tsum[m][r] += __shfl_xor(tsum[m][r], mask, 64);
#pragma unroll
    for (int m = 0; m < 4; ++m)
#pragma unroll
      for (int r = 0; r < 4; ++r)
        rl[m][r] = rl[m][r] * fac[m][r] + tsum[m][r];
#pragma unroll
    for (int m = 0; m < 4; ++m)
#pragma unroll
      for (int n = 0; n < 4; ++n)
#pragma unroll
        for (int r = 0; r < 4; ++r) xa[m][n][r] *= fac[m][r];

    // ---- PV ----  (P from per-wave LDS; Vt rows give contiguous j)
#pragma unroll
    for (int kk = 0; kk < 2; ++kk) {
      f16x8 pa[4], vf[4];
#pragma unroll
      for (int m = 0; m < 4; ++m)
        pa[m] = *(const f16x8*)&lP[wid][(m * 16 + r15) * 64 + kk * 32 + hi * 8];
#pragma unroll
      for (int n = 0; n < 4; ++n)
        vf[n] = *(const f16x8*)&lV[(n * 16 + r15) * 64 + kk * 32 + hi * 8];
#pragma unroll
      for (int m = 0; m < 4; ++m)
#pragma unroll
        for (int n = 0; n < 4; ++n)
          xa[m][n] = __builtin_amdgcn_mfma_f32_16x16x32_f16(pa[m], vf[n], xa[m][n], 0, 0, 0);
    }
    __syncthreads();
  }

  // write x = xa / rl
#pragma unroll
  for (int m = 0; m < 4; ++m) {
    int row0 = q0 + m * 16 + hi * 4;
#pragma unroll
    for (int n = 0; n < 4; ++n) {
      int col = h * DH_ + n * 16 + r15;
#pragma unroll
      for (int r = 0; r < 4; ++r)
        x[((size_t)(b * S_ + row0 + r)) * N_ + col] = (f16)(xa[m][n][r] / rl[m][r]);
    }
  }
}

// ---------------------------------------------------------------------------
extern "C" void kernel_launch(void* const* d_in, const int* in_sizes, int n_in,
                              void* d_out, int out_size, void* d_ws, size_t ws_size,
                              hipStream_t stream) {
  const float* inq  = (const float*)d_in[0];
  const float* inkv = (const float*)d_in[1];
  const float* Wq = (const float*)d_in[2];
  const float* bq = (const float*)d_in[3];
  const float* Wk = (const float*)d_in[4];
  const float* bk = (const float*)d_in[5];
  const float* Wv = (const float*)d_in[6];
  const float* bv = (const float*)d_in[7];
  const float* Wo = (const float*)d_in[8];
  const float* bo = (const float*)d_in[9];
  float* out = (float*)d_out;

  char* ws = (char*)d_ws;
  const size_t MB = 1024 * 1024;
  f16* h_inq  = (f16*)(ws + 0);         // 16MB, later reused as vt
  f16* h_inkv = (f16*)(ws + 16 * MB);   // 16MB, later reused as x
  f16* h_WqT  = (f16*)(ws + 32 * MB);   // 2MB each
  f16* h_WkT  = (f16*)(ws + 34 * MB);
  f16* h_WvT  = (f16*)(ws + 36 * MB);
  f16* h_WoT  = (f16*)(ws + 38 * MB);
  f16* h_q    = (f16*)(ws + 40 * MB);   // 16MB
  f16* h_k    = (f16*)(ws + 56 * MB);   // 16MB
  f16* h_v    = (f16*)(ws + 72 * MB);   // 16MB
  f16* h_vt   = h_inq;                  // alias (inq dead after q GEMM)
  f16* h_x    = h_inkv;                 // alias (inkv dead after k,v GEMMs)

  const int nIn  = M_ * D_;             // 8388608
  // 1. casts
  cvt_f32_f16<<<nIn / 4 / 256, 256, 0, stream>>>(inq,  h_inq,  nIn / 4);
  cvt_f32_f16<<<nIn / 4 / 256, 256, 0, stream>>>(inkv, h_inkv, nIn / 4);
  // 2. weight transposes
  transpose_w<<<dim3(32, 32, 4), dim3(32, 8), 0, stream>>>(
      Wq, Wk, Wv, Wo, h_WqT, h_WkT, h_WvT, h_WoT);
  // 3. QKV projections (q scaled by 1/sqrt(DH)=1/8, applied after bias)
  dim3 ggrid(N_ / 128, M_ / 128);
  gemm_bt<false><<<ggrid, 256, 0, stream>>>(h_inq,  h_WqT, bq, 0.125f, h_q, M_, N_, D_);
  gemm_bt<false><<<ggrid, 256, 0, stream>>>(h_inkv, h_WkT, bk, 1.0f,   h_k, M_, N_, D_);
  gemm_bt<false><<<ggrid, 256, 0, stream>>>(h_inkv, h_WvT, bv, 1.0f,   h_v, M_, N_, D_);
  // 4. v -> vt
  transpose_v<<<dim3(S_ / 64, B_ * H_), 256, 0, stream>>>(h_v, h_vt);
  // 5. attention
  attn<<<dim3(S_ / 256, B_ * H_), 256, 0, stream>>>(h_q, h_k, h_vt, h_x);
  // 6. output projection (f32 out)
  gemm_bt<true><<<ggrid, 256, 0, stream>>>(h_x, h_WoT, bo, 1.0f, out, M_, D_, N_);
}

// Round 3
// 366.328 us; speedup vs baseline: 1.4718x; 1.4718x over previous
//
#include <hip/hip_runtime.h>
#include <hip/hip_bf16.h>
#include <hip/hip_fp16.h>
#include <math.h>

// Problem dims
#define B_   4
#define S_   2048
#define D_   1024
#define H_   16
#define DH_  64
#define M_   (B_ * S_)      // 8192
#define N_   (H_ * DH_)     // 1024

typedef _Float16 f16;
typedef __attribute__((ext_vector_type(2))) _Float16 f16x2;
typedef __attribute__((ext_vector_type(4))) _Float16 f16x4;
typedef __attribute__((ext_vector_type(8))) _Float16 f16x8;
typedef __attribute__((ext_vector_type(4))) float    f32x4;

union H8 { f16x8 v; f16x4 q[2]; f16x2 d[4]; };
union PK { __half2 h2; f16x2 v; };

// device-safe 2^x (glibc's __exp2f is a host symbol — cannot be used)
#if __has_builtin(__builtin_amdgcn_exp2f)
__device__ __forceinline__ float exp2_fast(float x) { return __builtin_amdgcn_exp2f(x); }
#else
__device__ __forceinline__ float exp2_fast(float x) {
  float r; asm("v_exp_f32 %0, %1" : "=v"(r) : "v"(x)); return r;
}
#endif

// ---------------------------------------------------------------------------
// async global -> LDS, 16B per lane. LDS dest must be wave-uniform base;
// HW writes base + lane*16.
__device__ __forceinline__ void async_cp16(const void* g, void* l) {
  __builtin_amdgcn_global_load_lds(
      (const __attribute__((address_space(1))) unsigned int*)g,
      (__attribute__((address_space(3))) unsigned int*)l, 16, 0, 0);
}

// ---------------------------------------------------------------------------
// f32 -> f16 elementwise (vectorized 4-wide)
__global__ __launch_bounds__(256) void cvt_f32_f16(const float* __restrict__ in,
                                                   f16* __restrict__ out, int n4) {
  int i = blockIdx.x * 256 + threadIdx.x;
  if (i < n4) {
    f32x4 v = ((const f32x4*)in)[i];
    ((f16x4*)out)[i] = __builtin_convertvector(v, f16x4);
  }
}

// ---------------------------------------------------------------------------
// Weight transpose+cast: W [1024 x 1024] f32 row-major -> Wt [1024 x 1024] f16
__global__ __launch_bounds__(256) void transpose_w(
    const float* __restrict__ W0, const float* __restrict__ W1,
    const float* __restrict__ W2, const float* __restrict__ W3,
    f16* __restrict__ T0, f16* __restrict__ T1,
    f16* __restrict__ T2, f16* __restrict__ T3) {
  const float* W = (blockIdx.z == 0) ? W0 : (blockIdx.z == 1) ? W1
                 : (blockIdx.z == 2) ? W2 : W3;
  f16* T = (blockIdx.z == 0) ? T0 : (blockIdx.z == 1) ? T1
         : (blockIdx.z == 2) ? T2 : T3;
  __shared__ float tile[32][33];
  int x  = blockIdx.x * 32 + threadIdx.x;
  int y0 = blockIdx.y * 32 + threadIdx.y;
#pragma unroll
  for (int i = 0; i < 32; i += 8)
    tile[threadIdx.y + i][threadIdx.x] = W[(size_t)(y0 + i) * 1024 + x];
  __syncthreads();
  int tx  = blockIdx.y * 32 + threadIdx.x;
  int ty0 = blockIdx.x * 32 + threadIdx.y;
#pragma unroll
  for (int i = 0; i < 32; i += 8)
    T[(size_t)(ty0 + i) * 1024 + tx] = (f16)tile[threadIdx.x][threadIdx.y + i];
}

// ---------------------------------------------------------------------------
// v [B,S,H,DH] f16  ->  vt [B,H,DH,S] f16
__global__ __launch_bounds__(256) void transpose_v(const f16* __restrict__ v,
                                                   f16* __restrict__ vt) {
  int bh = blockIdx.y;
  int b  = bh >> 4, h = bh & 15;
  int s0 = blockIdx.x * 64;
  __shared__ f16 tile[64][72];
  int tid = threadIdx.x;
#pragma unroll
  for (int it = 0; it < 16; ++it) {
    int idx = it * 256 + tid;
    int r = idx >> 6, c = idx & 63;
    tile[r][c] = v[((size_t)(b * S_ + s0 + r)) * N_ + h * DH_ + c];
  }
  __syncthreads();
#pragma unroll
  for (int it = 0; it < 16; ++it) {
    int idx = it * 256 + tid;
    int fr = idx >> 6, sc = idx & 63;
    vt[((size_t)bh * DH_ + fr) * S_ + s0 + sc] = tile[sc][fr];
  }
}

// ---------------------------------------------------------------------------
// GEMM: C[M,N] = A[M,K] * Bt[N,K]^T, f16 in, f32 accum.
// 128x128 tile, BK=64, 256 threads (2x2 waves). Flattened 1D grid with
// bijective XCD swizzle (requires gridDim.x % 8 == 0 — true here, 512).
template <bool OUT_F32>
__global__ __launch_bounds__(256) void gemm_bt(
    const f16* __restrict__ A, const f16* __restrict__ Bt,
    const float* __restrict__ bias, float scale,
    void* __restrict__ outp, int M, int N, int K) {
  __shared__ f16 lA[128 * 64];
  __shared__ f16 lB[128 * 64];
  const int nbx = N >> 7;
  const int cpx = gridDim.x >> 3;
  const int wg  = (blockIdx.x & 7) * cpx + (blockIdx.x >> 3);
  const int tile_m = (wg / nbx) * 128, tile_n = (wg % nbx) * 128;
  const int tid  = threadIdx.x;
  const int lane = tid & 63, wid = tid >> 6;
  const int wr = wid >> 1, wc = wid & 1;
  const int l8 = lane >> 3, c8 = (lane & 7) * 8;
  const int r15 = lane & 15, hi = lane >> 4;

  f32x4 acc[4][4];
#pragma unroll
  for (int m = 0; m < 4; ++m)
#pragma unroll
    for (int n = 0; n < 4; ++n) acc[m][n] = (f32x4)(0.f);

  for (int kt = 0; kt < K; kt += 64) {
#pragma unroll
    for (int i = 0; i < 4; ++i) {
      int rb = wid * 32 + i * 8;
      async_cp16(A  + (size_t)(tile_m + rb + l8) * K + kt + c8, &lA[rb * 64]);
      async_cp16(Bt + (size_t)(tile_n + rb + l8) * K + kt + c8, &lB[rb * 64]);
    }
    __syncthreads();
#pragma unroll
    for (int kk = 0; kk < 2; ++kk) {
      f16x8 af[4], bf[4];
#pragma unroll
      for (int m = 0; m < 4; ++m)
        af[m] = *(const f16x8*)&lA[(wr * 64 + m * 16 + r15) * 64 + kk * 32 + hi * 8];
#pragma unroll
      for (int n = 0; n < 4; ++n)
        bf[n] = *(const f16x8*)&lB[(wc * 64 + n * 16 + r15) * 64 + kk * 32 + hi * 8];
#pragma unroll
      for (int m = 0; m < 4; ++m)
#pragma unroll
        for (int n = 0; n < 4; ++n)
          acc[m][n] = __builtin_amdgcn_mfma_f32_16x16x32_f16(af[m], bf[n], acc[m][n], 0, 0, 0);
    }
    __syncthreads();
  }

#pragma unroll
  for (int m = 0; m < 4; ++m) {
    int row0 = tile_m + wr * 64 + m * 16 + hi * 4;
#pragma unroll
    for (int n = 0; n < 4; ++n) {
      int col = tile_n + wc * 64 + n * 16 + r15;
      float bv = bias[col];
#pragma unroll
      for (int r = 0; r < 4; ++r) {
        float v = (acc[m][n][r] + bv) * scale;
        if (OUT_F32)
          ((float*)outp)[(size_t)(row0 + r) * N + col] = v;
        else
          ((f16*)outp)[(size_t)(row0 + r) * N + col] = (f16)v;
      }
    }
  }
}

// ---------------------------------------------------------------------------
// Flash attention, fully-swapped operands:
//   S^T = mfma(K, Q)  -> lane holds S-values for q-col (lane&15)
//   x^T = mfma(Vt, P) -> P fragment built entirely in-register via a
//   consistent k-permutation sigma(kk,hi,jj) = 32kk + 16(jj>>2) + 4hi + (jj&3)
//   applied to BOTH operands (V^T reads and P packing), so no cross-lane
//   exchange is needed for P.
// K/V tiles (64x64 f16, rows = 128B) double-buffered in LDS with XOR swizzle
// byte ^= ((row&7)<<4), achieved via pre-swizzled global_load_lds SOURCE
// addresses (linear LDS dest) + swizzled ds_read addresses.
// q is pre-scaled by (1/8)*log2(e) so softmax uses exp2 directly.
__global__ __launch_bounds__(256, 2) void attn(
    const f16* __restrict__ q, const f16* __restrict__ k,
    const f16* __restrict__ vt, f16* __restrict__ x) {
  __shared__ f16 lK[2][64 * 64];
  __shared__ f16 lV[2][64 * 64];
  const int tid = threadIdx.x, lane = tid & 63, wid = tid >> 6;
  const int bh = blockIdx.y, b = bh >> 4, h = bh & 15;
  const int q0 = blockIdx.x * 256 + wid * 64;
  const int c15 = lane & 15, hi = lane >> 4;
  const int swr = (c15 & 7) << 4;                 // read-side XOR (bytes)
  const int swz = 8 * ((lane & 7) ^ (lane >> 3)); // staging source col (elems)
  const int lrow = lane >> 3;                     // staging source row in chunk

  const f16* qb = q  + (size_t)b * S_ * N_ + h * DH_;
  const f16* kb = k  + (size_t)b * S_ * N_ + h * DH_;
  const f16* vb = vt + (size_t)bh * DH_ * S_;

  // Q fragments (B-operand): q-row q0+qm*16+c15, k-elems kk*32+hi*8
  f16x8 qf[4][2];
#pragma unroll
  for (int qm = 0; qm < 4; ++qm)
#pragma unroll
    for (int kk = 0; kk < 2; ++kk)
      qf[qm][kk] = *(const f16x8*)(qb + (size_t)(q0 + qm * 16 + c15) * N_ + kk * 32 + hi * 8);

  f32x4 xa[4][4];   // [fn][qm], x^T: rows f, cols q
#pragma unroll
  for (int fn = 0; fn < 4; ++fn)
#pragma unroll
    for (int qm = 0; qm < 4; ++qm) xa[fn][qm] = (f32x4)(0.f);
  float rm[4], rl[4];
#pragma unroll
  for (int qm = 0; qm < 4; ++qm) { rm[qm] = -INFINITY; rl[qm] = 0.f; }

  auto STAGE = [&](int t, int buf) {
    int j0 = t * 64;
#pragma unroll
    for (int i = 0; i < 2; ++i) {
      int rb = wid * 16 + i * 8;
      async_cp16(kb + (size_t)(j0 + rb + lrow) * N_ + swz, &lK[buf][rb * 64]);
      async_cp16(vb + (size_t)(rb + lrow) * S_ + j0 + swz, &lV[buf][rb * 64]);
    }
  };

  STAGE(0, 0);
  __syncthreads();

  for (int t = 0; t < S_ / 64; ++t) {
    const int cur = t & 1;
    if (t < S_ / 64 - 1) STAGE(t + 1, cur ^ 1);

    // K fragments (A-operand): rows j = jn*16+c15, swizzled read
    f16x8 kf[4][2];
#pragma unroll
    for (int jn = 0; jn < 4; ++jn) {
      int rowe = (jn * 16 + c15) * 64;
#pragma unroll
      for (int kk = 0; kk < 2; ++kk)
        kf[jn][kk] = *(const f16x8*)&lK[cur][rowe + (((kk * 64 + hi * 16) ^ swr) >> 1)];
    }

    f16x8 bfrag[4][2];
#pragma unroll
    for (int qm = 0; qm < 4; ++qm) {
      // S^T tile: sq[jn][r] = S[q = qm*16+c15][j = jn*16 + hi*4 + r]
      f32x4 sq[4];
#pragma unroll
      for (int jn = 0; jn < 4; ++jn) sq[jn] = (f32x4)(0.f);
#pragma unroll
      for (int kk = 0; kk < 2; ++kk)
#pragma unroll
        for (int jn = 0; jn < 4; ++jn)
          sq[jn] = __builtin_amdgcn_mfma_f32_16x16x32_f16(kf[jn][kk], qf[qm][kk], sq[jn], 0, 0, 0);

      // online softmax (log2 domain): in-lane max of 16, then 2 shfl steps
      float mx = sq[0][0];
#pragma unroll
      for (int jn = 0; jn < 4; ++jn)
#pragma unroll
        for (int r = 0; r < 4; ++r) mx = fmaxf(mx, sq[jn][r]);
      mx = fmaxf(mx, __shfl_xor(mx, 16));
      mx = fmaxf(mx, __shfl_xor(mx, 32));
      float nm  = fmaxf(rm[qm], mx);
      float fac = exp2_fast(rm[qm] - nm);
      rm[qm] = nm;

      float p[4][4], ts = 0.f;
#pragma unroll
      for (int jn = 0; jn < 4; ++jn)
#pragma unroll
        for (int r = 0; r < 4; ++r) {
          p[jn][r] = exp2_fast(sq[jn][r] - nm);
          ts += p[jn][r];
        }
      ts += __shfl_xor(ts, 16);
      ts += __shfl_xor(ts, 32);
      rl[qm] = rl[qm] * fac + ts;
#pragma unroll
      for (int fn = 0; fn < 4; ++fn)
#pragma unroll
        for (int r = 0; r < 4; ++r) xa[fn][qm][r] *= fac;

      // pack P -> f16 B-fragments: bfrag[kk] = {p[2kk][0..3], p[2kk+1][0..3]}
      PK w[4][2];
#pragma unroll
      for (int jn = 0; jn < 4; ++jn)
#pragma unroll
        for (int hh = 0; hh < 2; ++hh)
          w[jn][hh].h2 = __floats2half2_rn(p[jn][2 * hh], p[jn][2 * hh + 1]);
#pragma unroll
      for (int kk = 0; kk < 2; ++kk) {
        H8 u;
        u.d[0] = w[2 * kk][0].v;     u.d[1] = w[2 * kk][1].v;
        u.d[2] = w[2 * kk + 1][0].v; u.d[3] = w[2 * kk + 1][1].v;
        bfrag[qm][kk] = u.v;
      }
    }

    // PV: x^T += Vt * P.  A-frag element jj = V^T[f][32kk + 16(jj>>2) + 4hi + (jj&3)]
    // -> two swizzled ds_read_b64 per (fn,kk).
#pragma unroll
    for (int kk = 0; kk < 2; ++kk)
#pragma unroll
      for (int fn = 0; fn < 4; ++fn) {
        int rowe = (fn * 16 + c15) * 64;
        H8 u;
        u.q[0] = *(const f16x4*)&lV[cur][rowe + (((kk * 64 + hi * 8) ^ swr) >> 1)];
        u.q[1] = *(const f16x4*)&lV[cur][rowe + (((kk * 64 + 32 + hi * 8) ^ swr) >> 1)];
#pragma unroll
        for (int qm = 0; qm < 4; ++qm)
          xa[fn][qm] = __builtin_amdgcn_mfma_f32_16x16x32_f16(u.v, bfrag[qm][kk], xa[fn][qm], 0, 0, 0);
      }
    __syncthreads();
  }

  // epilogue: x[q][h*64+f] = xa / rl   (4 contiguous f per (fn,qm) -> 8B store)
  float inv[4];
#pragma unroll
  for (int qm = 0; qm < 4; ++qm) inv[qm] = 1.f / rl[qm];
#pragma unroll
  for (int qm = 0; qm < 4; ++qm) {
    size_t rowb = (size_t)(b * S_ + q0 + qm * 16 + c15) * N_ + h * DH_;
#pragma unroll
    for (int fn = 0; fn < 4; ++fn) {
      f16x4 o;
#pragma unroll
      for (int r = 0; r < 4; ++r) o[r] = (f16)(xa[fn][qm][r] * inv[qm]);
      *(f16x4*)(x + rowb + fn * 16 + hi * 4) = o;
    }
  }
}

// ---------------------------------------------------------------------------
extern "C" void kernel_launch(void* const* d_in, const int* in_sizes, int n_in,
                              void* d_out, int out_size, void* d_ws, size_t ws_size,
                              hipStream_t stream) {
  const float* inq  = (const float*)d_in[0];
  const float* inkv = (const float*)d_in[1];
  const float* Wq = (const float*)d_in[2];
  const float* bq = (const float*)d_in[3];
  const float* Wk = (const float*)d_in[4];
  const float* bk = (const float*)d_in[5];
  const float* Wv = (const float*)d_in[6];
  const float* bv = (const float*)d_in[7];
  const float* Wo = (const float*)d_in[8];
  const float* bo = (const float*)d_in[9];
  float* out = (float*)d_out;

  char* ws = (char*)d_ws;
  const size_t MB = 1024 * 1024;
  f16* h_inq  = (f16*)(ws + 0);         // 16MB, later reused as vt
  f16* h_inkv = (f16*)(ws + 16 * MB);   // 16MB, later reused as x
  f16* h_WqT  = (f16*)(ws + 32 * MB);
  f16* h_WkT  = (f16*)(ws + 34 * MB);
  f16* h_WvT  = (f16*)(ws + 36 * MB);
  f16* h_WoT  = (f16*)(ws + 38 * MB);
  f16* h_q    = (f16*)(ws + 40 * MB);
  f16* h_k    = (f16*)(ws + 56 * MB);
  f16* h_v    = (f16*)(ws + 72 * MB);
  f16* h_vt   = h_inq;                  // alias (inq dead after q GEMM)
  f16* h_x    = h_inkv;                 // alias (inkv dead after k,v GEMMs)

  const int nIn = M_ * D_;
  cvt_f32_f16<<<nIn / 4 / 256, 256, 0, stream>>>(inq,  h_inq,  nIn / 4);
  cvt_f32_f16<<<nIn / 4 / 256, 256, 0, stream>>>(inkv, h_inkv, nIn / 4);
  transpose_w<<<dim3(32, 32, 4), dim3(32, 8), 0, stream>>>(
      Wq, Wk, Wv, Wo, h_WqT, h_WkT, h_WvT, h_WoT);
  // q scale folds 1/sqrt(DH) and log2(e) for the exp2-domain softmax
  const float qscale = 0.125f * 1.4426950408889634f;
  const int nwg = (M_ / 128) * (N_ / 128);   // 512, %8==0 for XCD swizzle
  gemm_bt<false><<<nwg, 256, 0, stream>>>(h_inq,  h_WqT, bq, qscale, h_q, M_, N_, D_);
  gemm_bt<false><<<nwg, 256, 0, stream>>>(h_inkv, h_WkT, bk, 1.0f,   h_k, M_, N_, D_);
  gemm_bt<false><<<nwg, 256, 0, stream>>>(h_inkv, h_WvT, bv, 1.0f,   h_v, M_, N_, D_);
  transpose_v<<<dim3(S_ / 64, B_ * H_), 256, 0, stream>>>(h_v, h_vt);
  attn<<<dim3(S_ / 256, B_ * H_), 256, 0, stream>>>(h_q, h_k, h_vt, h_x);
  gemm_bt<true><<<nwg, 256, 0, stream>>>(h_x, h_WoT, bo, 1.0f, out, M_, D_, N_);
}